// Round 3
// baseline (192.628 us; speedup 1.0000x reference)
//
#include <hip/hip_runtime.h>
#include <hip/hip_cooperative_groups.h>

namespace cg = cooperative_groups;

#define HW_TOTAL (4096 * 4096)
#define NBINS 256
#define NCHUNK (HW_TOTAL / 4)          // int4 chunks = 4M
#define GRID_B 256                     // one block per CU, co-resident
#define BLK 1024                       // 16 waves/block
#define CPT (NCHUNK / (GRID_B * BLK))  // 16 chunks per thread
#define BATCH 8                        // int4 loads in flight per thread

// ws layout: ws[0] = thresh; +256 B: partials[GRID_B][NBINS] (u32)
#define WS_NEED (GRID_B * NBINS * 4 + 256)

// ---------------------------------------------------------------------------
// Fused cooperative kernel: hist -> grid.sync -> reduce+threshold (block 0)
// -> grid.sync -> binarize. Image re-read in phase C is L3-resident.
// ---------------------------------------------------------------------------
__global__ __launch_bounds__(BLK, 4) void otsu_fused_k(const int* __restrict__ img,
                                                       int* __restrict__ out,
                                                       int* __restrict__ ws) {
    cg::grid_group grid = cg::this_grid();

    __shared__ unsigned h[4 * NBINS];     // bank-interleaved: h[(bin<<2)|sub]
    __shared__ unsigned red[4][NBINS];
    __shared__ unsigned cnt[NBINS];

    unsigned* partials = (unsigned*)ws + 64;   // +256 B
    const int t = threadIdx.x;
    const int b = blockIdx.x;
    const int4* img4 = (const int4*)img;
    const int base = b * (BLK * CPT);

    // ---------------- Phase A: histogram ----------------
    for (int i = t; i < 4 * NBINS; i += BLK) h[i] = 0;
    __syncthreads();

    const unsigned sub = (unsigned)t & 3u;
    for (int ob = 0; ob < CPT / BATCH; ++ob) {
        int4 v[BATCH];
        const int i0 = base + ob * (BLK * BATCH) + t;
#pragma unroll
        for (int k = 0; k < BATCH; ++k) v[k] = img4[i0 + k * BLK];
#pragma unroll
        for (int k = 0; k < BATCH; ++k) {
            atomicAdd(&h[(((unsigned)v[k].x) << 2) | sub], 1u);
            atomicAdd(&h[(((unsigned)v[k].y) << 2) | sub], 1u);
            atomicAdd(&h[(((unsigned)v[k].z) << 2) | sub], 1u);
            atomicAdd(&h[(((unsigned)v[k].w) << 2) | sub], 1u);
        }
    }
    __syncthreads();
    if (t < NBINS) {
        unsigned s = h[t << 2] + h[(t << 2) | 1] + h[(t << 2) | 2] + h[(t << 2) | 3];
        partials[b * NBINS + t] = s;
    }
    __threadfence();
    grid.sync();

    // ---------------- Phase B: reduce + Otsu threshold (block 0) ----------------
    if (b == 0) {
        const int bin = t & 255;
        const int q = t >> 8;              // 4 groups of 64 rows each
        unsigned s = 0;
        for (int r = q * 64; r < q * 64 + 64; r += 8) {
#pragma unroll
            for (int k = 0; k < 8; ++k) s += partials[(r + k) * NBINS + bin];
        }
        red[q][bin] = s;
        __syncthreads();
        if (t < NBINS)
            cnt[t] = red[0][t] + red[1][t] + red[2][t] + red[3][t];
        __syncthreads();

        if (t < 64) {
            const int lane = t;
            uint4 c4 = ((const uint4*)cnt)[lane];
            unsigned cs[4] = {c4.x, c4.y, c4.z, c4.w};

            unsigned long long lc[4], lv[4];
            unsigned long long ccum = 0ull, vcum = 0ull;
#pragma unroll
            for (int k = 0; k < 4; ++k) {
                ccum += cs[k];
                vcum += (unsigned long long)cs[k] * (unsigned)(4 * lane + k);
                lc[k] = ccum;
                lv[k] = vcum;
            }
            unsigned long long cscan = ccum, vscan = vcum;
            for (int d = 1; d < 64; d <<= 1) {
                unsigned long long cu = __shfl_up(cscan, d);
                unsigned long long vu = __shfl_up(vscan, d);
                if (lane >= d) { cscan += cu; vscan += vu; }
            }
            const unsigned long long cbase = cscan - ccum;
            const unsigned long long vbase = vscan - vcum;
            const unsigned long long vtotal = __shfl(vscan, 63);

            double best = -1.0;
            int bestt = 255;
            const double hw = (double)HW_TOTAL;
            const double vtot_d = (double)vtotal;
#pragma unroll
            for (int k = 0; k < 4; ++k) {
                int tt = 4 * lane + k;
                if (tt > 254) continue;
                double nb = (double)(cbase + lc[k]);
                double sb = (double)(vbase + lv[k]);
                double nw = hw - nb;
                double sw = vtot_d - sb;
                double mb = sb / nb;
                double mw = sw / nw;
                double dm = mb - mw;
                double var = nb * nw * dm * dm;
                if (var > best || (var == best && tt < bestt)) { best = var; bestt = tt; }
            }
            for (int d = 32; d >= 1; d >>= 1) {
                double ov = __shfl_xor(best, d);
                int ot = __shfl_xor(bestt, d);
                if (ov > best || (ov == best && ot < bestt)) { best = ov; bestt = ot; }
            }
            if (lane == 0) {
                out[0] = bestt;
                ws[0] = bestt;
            }
        }
        __threadfence();
    }
    grid.sync();

    // ---------------- Phase C: binarize (shifted aligned stores) ----------------
    const int thresh = ws[0];
    const int lane = t & 63;
    for (int ob = 0; ob < CPT / BATCH; ++ob) {
        int4 v[BATCH];
        const int i0 = base + ob * (BLK * BATCH) + t;
#pragma unroll
        for (int k = 0; k < BATCH; ++k) v[k] = img4[i0 + k * BLK];
#pragma unroll
        for (int k = 0; k < BATCH; ++k) {
            const int c = i0 + k * BLK;
            int prev = __shfl_up(v[k].w, 1);
            if (lane == 0) prev = (c > 0) ? img[4 * c - 1] : 0;
            int4 o;
            o.x = (c == 0) ? thresh : ((prev <= thresh) ? 0 : 256);
            o.y = (v[k].x <= thresh) ? 0 : 256;
            o.z = (v[k].y <= thresh) ? 0 : 256;
            o.w = (v[k].z <= thresh) ? 0 : 256;
            ((int4*)out)[c] = o;
        }
    }
    if (b == 0 && t == 0)
        out[HW_TOTAL] = (img[HW_TOTAL - 1] <= thresh) ? 0 : 256;
}

// ---------------------------------------------------------------------------
// Fallback path (ws too small): 3-kernel atomic scheme (proven in round 1/2).
// ---------------------------------------------------------------------------
__global__ __launch_bounds__(256) void fb_hist_k(const int4* __restrict__ img4,
                                                 unsigned* __restrict__ ghist) {
    __shared__ unsigned h[4 * NBINS];
    for (int i = threadIdx.x; i < 4 * NBINS; i += 256) h[i] = 0;
    __syncthreads();
    const unsigned sub = (unsigned)threadIdx.x & 3u;
    const int base = blockIdx.x * (NCHUNK / 512);
    for (int ob = 0; ob < (NCHUNK / 512) / (256 * BATCH); ++ob) {
        int4 v[BATCH];
        const int i0 = base + ob * (256 * BATCH) + threadIdx.x;
#pragma unroll
        for (int k = 0; k < BATCH; ++k) v[k] = img4[i0 + k * 256];
#pragma unroll
        for (int k = 0; k < BATCH; ++k) {
            atomicAdd(&h[(((unsigned)v[k].x) << 2) | sub], 1u);
            atomicAdd(&h[(((unsigned)v[k].y) << 2) | sub], 1u);
            atomicAdd(&h[(((unsigned)v[k].z) << 2) | sub], 1u);
            atomicAdd(&h[(((unsigned)v[k].w) << 2) | sub], 1u);
        }
    }
    __syncthreads();
    const int i = threadIdx.x;
    if (i < NBINS) {
        unsigned s = h[i << 2] + h[(i << 2) | 1] + h[(i << 2) | 2] + h[(i << 2) | 3];
        if (s) atomicAdd(&ghist[i], s);
    }
}

__global__ __launch_bounds__(64) void fb_thresh_k(const unsigned* __restrict__ cnt,
                                                  int* __restrict__ d_out,
                                                  int* __restrict__ thresh_ws) {
    const int lane = threadIdx.x;
    uint4 c4 = ((const uint4*)cnt)[lane];
    unsigned cs[4] = {c4.x, c4.y, c4.z, c4.w};
    unsigned long long lc[4], lv[4], ccum = 0ull, vcum = 0ull;
#pragma unroll
    for (int k = 0; k < 4; ++k) {
        ccum += cs[k];
        vcum += (unsigned long long)cs[k] * (unsigned)(4 * lane + k);
        lc[k] = ccum; lv[k] = vcum;
    }
    unsigned long long cscan = ccum, vscan = vcum;
    for (int d = 1; d < 64; d <<= 1) {
        unsigned long long cu = __shfl_up(cscan, d);
        unsigned long long vu = __shfl_up(vscan, d);
        if (lane >= d) { cscan += cu; vscan += vu; }
    }
    const unsigned long long cbase = cscan - ccum, vbase = vscan - vcum;
    const unsigned long long vtotal = __shfl(vscan, 63);
    double best = -1.0; int bestt = 255;
#pragma unroll
    for (int k = 0; k < 4; ++k) {
        int tt = 4 * lane + k;
        if (tt > 254) continue;
        double nb = (double)(cbase + lc[k]), sb = (double)(vbase + lv[k]);
        double nw = (double)HW_TOTAL - nb, sw = (double)vtotal - sb;
        double dm = sb / nb - sw / nw;
        double var = nb * nw * dm * dm;
        if (var > best || (var == best && tt < bestt)) { best = var; bestt = tt; }
    }
    for (int d = 32; d >= 1; d >>= 1) {
        double ov = __shfl_xor(best, d);
        int ot = __shfl_xor(bestt, d);
        if (ov > best || (ov == best && ot < bestt)) { best = ov; bestt = ot; }
    }
    if (lane == 0) { d_out[0] = bestt; *thresh_ws = bestt; }
}

__global__ __launch_bounds__(256) void fb_bin_k(const int* __restrict__ img,
                                                int* __restrict__ out,
                                                const int* __restrict__ thresh_ws) {
    const int thresh = *thresh_ws;
    const int base = blockIdx.x * 1024;
    const int lane = threadIdx.x & 63;
#pragma unroll
    for (int k = 0; k < 4; ++k) {
        const int c = base + k * 256 + threadIdx.x;
        int4 v = ((const int4*)img)[c];
        int prev = __shfl_up(v.w, 1);
        if (lane == 0) prev = (c > 0) ? img[4 * c - 1] : 0;
        int4 o;
        o.x = (c == 0) ? thresh : ((prev <= thresh) ? 0 : 256);
        o.y = (v.x <= thresh) ? 0 : 256;
        o.z = (v.y <= thresh) ? 0 : 256;
        o.w = (v.z <= thresh) ? 0 : 256;
        ((int4*)out)[c] = o;
    }
    if (blockIdx.x == 0 && threadIdx.x == 0)
        out[HW_TOTAL] = (img[HW_TOTAL - 1] <= thresh) ? 0 : 256;
}

extern "C" void kernel_launch(void* const* d_in, const int* in_sizes, int n_in,
                              void* d_out, int out_size, void* d_ws, size_t ws_size,
                              hipStream_t stream) {
    const int* img = (const int*)d_in[0];
    int* out = (int*)d_out;
    int* ws = (int*)d_ws;

    if (ws_size >= (size_t)WS_NEED) {
        void* args[] = {(void*)&img, (void*)&out, (void*)&ws};
        hipLaunchCooperativeKernel((const void*)otsu_fused_k, dim3(GRID_B), dim3(BLK),
                                   args, 0, stream);
    } else {
        int* thresh_ws = ws;
        unsigned* ghist = (unsigned*)((char*)d_ws + 256);
        hipMemsetAsync(ghist, 0, NBINS * sizeof(unsigned), stream);
        fb_hist_k<<<512, 256, 0, stream>>>((const int4*)img, ghist);
        fb_thresh_k<<<1, 64, 0, stream>>>(ghist, out, thresh_ws);
        fb_bin_k<<<NCHUNK / 1024, 256, 0, stream>>>(img, out, thresh_ws);
    }
}

// Round 5
// 45.820 us; speedup vs baseline: 4.2040x; 4.2040x over previous
//
#include <hip/hip_runtime.h>

#define HW_TOTAL (4096 * 4096)
#define NBINS 256
#define NCHUNK (HW_TOTAL / 4)          // int4 chunks = 4M
#define HIST_B 512                     // histogram blocks
#define BLK 1024                       // threads per block (16 waves)
#define BATCH 8                        // int4 loads in flight per thread
// 512 blocks * 1024 threads * 8 chunks = 4M chunks exactly.

typedef int int4n __attribute__((ext_vector_type(4)));   // native vec for nt-store

// ws layout: ws[0] = thresh; +256 B: partials[HIST_B][NBINS] (u32)
#define WS_NEED (HIST_B * NBINS * 4 + 256)

// ---------------------------------------------------------------------------
// Kernel 1: histogram. Bank-interleaved LDS sub-hists h[(bin<<2)|sub] so the
// 4 sub-copies of one bin land in 4 different banks. One batch of 8 int4
// loads per thread (all in flight before use). MODE 0: per-block partial
// store. MODE 1: global atomic flush (fallback when ws is tiny).
// ---------------------------------------------------------------------------
template <int MODE>
__global__ __launch_bounds__(BLK, 8) void otsu_hist_k(const int4* __restrict__ img4,
                                                      unsigned* __restrict__ out) {
    __shared__ unsigned h[4 * NBINS];
    const int t = threadIdx.x;
    for (int i = t; i < 4 * NBINS; i += BLK) h[i] = 0;
    __syncthreads();

    const unsigned sub = (unsigned)t & 3u;
    const int i0 = blockIdx.x * (BLK * BATCH) + t;
    int4 v[BATCH];
#pragma unroll
    for (int k = 0; k < BATCH; ++k) v[k] = img4[i0 + k * BLK];
#pragma unroll
    for (int k = 0; k < BATCH; ++k) {
        atomicAdd(&h[(((unsigned)v[k].x) << 2) | sub], 1u);
        atomicAdd(&h[(((unsigned)v[k].y) << 2) | sub], 1u);
        atomicAdd(&h[(((unsigned)v[k].z) << 2) | sub], 1u);
        atomicAdd(&h[(((unsigned)v[k].w) << 2) | sub], 1u);
    }
    __syncthreads();

    if (t < NBINS) {
        unsigned s = h[t << 2] + h[(t << 2) | 1] + h[(t << 2) | 2] + h[(t << 2) | 3];
        if (MODE == 0) {
            out[blockIdx.x * NBINS + t] = s;
        } else {
            if (s) atomicAdd(&out[t], s);
        }
    }
}

// ---------------------------------------------------------------------------
// Kernel 2: reduce B partial histograms + Otsu threshold. 1024 threads:
// thread (bin, q) sums rows in its quarter with 8-deep batched loads. Wave 0
// then does an exact uint64 prefix scan (shfl) + float64 variance argmax.
// val_sum[t] == t * cnt[t] exactly, so only the count histogram is needed.
// ---------------------------------------------------------------------------
__global__ __launch_bounds__(1024) void otsu_thresh_k(const unsigned* __restrict__ partials,
                                                      int B,
                                                      int* __restrict__ d_out,
                                                      int* __restrict__ thresh_ws) {
    __shared__ unsigned red[4][NBINS];
    __shared__ unsigned cnt[NBINS];

    const int bin = threadIdx.x & 255;
    const int q = threadIdx.x >> 8;
    const int BQ = (B + 3) / 4;
    int r = q * BQ;
    const int e = min((q + 1) * BQ, B);
    unsigned s = 0;
    for (; r + 8 <= e; r += 8) {
#pragma unroll
        for (int k = 0; k < 8; ++k) s += partials[(r + k) * NBINS + bin];
    }
    for (; r < e; ++r) s += partials[r * NBINS + bin];
    red[q][bin] = s;
    __syncthreads();

    if (threadIdx.x < NBINS)
        cnt[bin] = red[0][bin] + red[1][bin] + red[2][bin] + red[3][bin];
    __syncthreads();

    if (threadIdx.x >= 64) return;
    const int lane = threadIdx.x;

    uint4 c4 = ((const uint4*)cnt)[lane];
    unsigned cs[4] = {c4.x, c4.y, c4.z, c4.w};

    unsigned long long lc[4], lv[4];
    unsigned long long ccum = 0ull, vcum = 0ull;
#pragma unroll
    for (int k = 0; k < 4; ++k) {
        ccum += cs[k];
        vcum += (unsigned long long)cs[k] * (unsigned)(4 * lane + k);
        lc[k] = ccum;
        lv[k] = vcum;
    }
    unsigned long long cscan = ccum, vscan = vcum;
    for (int d = 1; d < 64; d <<= 1) {
        unsigned long long cu = __shfl_up(cscan, d);
        unsigned long long vu = __shfl_up(vscan, d);
        if (lane >= d) { cscan += cu; vscan += vu; }
    }
    const unsigned long long cbase = cscan - ccum;
    const unsigned long long vbase = vscan - vcum;
    const unsigned long long vtotal = __shfl(vscan, 63);

    double best = -1.0;
    int bestt = 255;
    const double hw = (double)HW_TOTAL;
    const double vtot_d = (double)vtotal;
#pragma unroll
    for (int k = 0; k < 4; ++k) {
        int tt = 4 * lane + k;
        if (tt > 254) continue;
        double nb = (double)(cbase + lc[k]);
        double sb = (double)(vbase + lv[k]);
        double nw = hw - nb;
        double sw = vtot_d - sb;
        double dm = sb / nb - sw / nw;
        double var = nb * nw * dm * dm;
        if (var > best || (var == best && tt < bestt)) { best = var; bestt = tt; }
    }
    for (int d = 32; d >= 1; d >>= 1) {
        double ov = __shfl_xor(best, d);
        int ot = __shfl_xor(bestt, d);
        if (ov > best || (ov == best && ot < bestt)) { best = ov; bestt = ot; }
    }
    if (lane == 0) {
        d_out[0] = bestt;
        *thresh_ws = bestt;
    }
}

// ---------------------------------------------------------------------------
// Kernel 3: binarize, 8 chunks per thread. Output image lives at out[1..HW],
// so aligned out-chunk out[4c..4c+3] = bin of pixels 4c-1..4c+2. Pixel 4c-1
// comes from the wave neighbor via shfl_up (lane 0: one scalar load).
// Nontemporal stores: out is never re-read, keep img resident in L2/L3.
// ---------------------------------------------------------------------------
__global__ __launch_bounds__(BLK, 8) void otsu_bin_k(const int* __restrict__ img,
                                                     int* __restrict__ out,
                                                     const int* __restrict__ thresh_ws) {
    const int thresh = *thresh_ws;
    const int t = threadIdx.x;
    const int lane = t & 63;
    const int i0 = blockIdx.x * (BLK * BATCH) + t;
    const int4* img4 = (const int4*)img;
#pragma unroll
    for (int k = 0; k < BATCH; ++k) {
        const int c = i0 + k * BLK;
        int4 v = img4[c];
        int prev = __shfl_up(v.w, 1);
        if (lane == 0) prev = (c > 0) ? img[4 * c - 1] : 0;
        int4n o;
        o.x = (c == 0) ? thresh : ((prev <= thresh) ? 0 : 256);
        o.y = (v.x <= thresh) ? 0 : 256;
        o.z = (v.y <= thresh) ? 0 : 256;
        o.w = (v.z <= thresh) ? 0 : 256;
        __builtin_nontemporal_store(o, (int4n*)out + c);
    }
    if (blockIdx.x == 0 && t == 0)
        out[HW_TOTAL] = (img[HW_TOTAL - 1] <= thresh) ? 0 : 256;
}

extern "C" void kernel_launch(void* const* d_in, const int* in_sizes, int n_in,
                              void* d_out, int out_size, void* d_ws, size_t ws_size,
                              hipStream_t stream) {
    const int* img = (const int*)d_in[0];
    int* out = (int*)d_out;
    int* thresh_ws = (int*)d_ws;
    unsigned* hist_buf = (unsigned*)((char*)d_ws + 256);

    if (ws_size >= (size_t)WS_NEED) {
        // partial-histogram scheme: no global atomics, no memset
        otsu_hist_k<0><<<HIST_B, BLK, 0, stream>>>((const int4*)img, hist_buf);
        otsu_thresh_k<<<1, 1024, 0, stream>>>(hist_buf, HIST_B, out, thresh_ws);
    } else {
        // fallback: atomic flush into a single 256-bin histogram
        (void)hipMemsetAsync(hist_buf, 0, NBINS * sizeof(unsigned), stream);
        otsu_hist_k<1><<<HIST_B, BLK, 0, stream>>>((const int4*)img, hist_buf);
        otsu_thresh_k<<<1, 1024, 0, stream>>>(hist_buf, 1, out, thresh_ws);
    }
    otsu_bin_k<<<HIST_B, BLK, 0, stream>>>(img, out, thresh_ws);
}

// Round 6
// 44.237 us; speedup vs baseline: 4.3544x; 1.0358x over previous
//
#include <hip/hip_runtime.h>

#define HW_TOTAL (4096 * 4096)
#define NBINS 256
#define NCHUNK (HW_TOTAL / 4)          // int4 chunks = 4M
#define HIST_B 512                     // blocks for hist/bin
#define BLK 1024                       // threads per block (16 waves)
#define BATCH 8                        // int4 chunks per thread
// 512 blocks * 1024 threads * 8 chunks = 4M chunks exactly.

typedef int int4n __attribute__((ext_vector_type(4)));                // aligned(16)
typedef int int4a __attribute__((ext_vector_type(4), aligned(4)));   // dword-aligned

// ws layout: ws[0] = thresh; +256 B: partials[HIST_B][NBINS] (u32)
#define WS_NEED (HIST_B * NBINS * 4 + 256)

// ---------------------------------------------------------------------------
// Kernel 1: histogram. LDS layout h[(bin<<2)|sub], sub = t&3: the 4 copies of
// a bin live in 4 different banks. Lean addressing: hp = h + sub, index v<<2
// -> single v_lshl_add per pixel + ds atomic. Wave-contiguous iteration:
// each wave's 8 iters cover one contiguous 8 KiB run.
// MODE 0: per-block partial store. MODE 1: global atomic flush (fallback).
// ---------------------------------------------------------------------------
template <int MODE>
__global__ __launch_bounds__(BLK, 8) void otsu_hist_k(const int4* __restrict__ img4,
                                                      unsigned* __restrict__ out) {
    __shared__ unsigned h[4 * NBINS];
    const int t = threadIdx.x;
    for (int i = t; i < 4 * NBINS; i += BLK) h[i] = 0;
    __syncthreads();

    unsigned* hp = h + (t & 3);        // sub-histogram base
    const int wave = t >> 6, lane = t & 63;
    const int i0 = blockIdx.x * (BLK * BATCH) + wave * (64 * BATCH) + lane;

    int4 v[BATCH];
#pragma unroll
    for (int k = 0; k < BATCH; ++k) v[k] = img4[i0 + k * 64];
#pragma unroll
    for (int k = 0; k < BATCH; ++k) {
        atomicAdd(&hp[((unsigned)v[k].x) << 2], 1u);
        atomicAdd(&hp[((unsigned)v[k].y) << 2], 1u);
        atomicAdd(&hp[((unsigned)v[k].z) << 2], 1u);
        atomicAdd(&hp[((unsigned)v[k].w) << 2], 1u);
    }
    __syncthreads();

    if (t < NBINS) {
        unsigned s = h[t << 2] + h[(t << 2) | 1] + h[(t << 2) | 2] + h[(t << 2) | 3];
        if (MODE == 0) {
            out[blockIdx.x * NBINS + t] = s;
        } else {
            if (s) atomicAdd(&out[t], s);
        }
    }
}

// ---------------------------------------------------------------------------
// Kernel 2: reduce B partial histograms + Otsu threshold. 1024 threads:
// thread (bin, q) sums its quarter of the rows with 16-deep batched loads.
// Wave 0 then does an exact uint64 prefix scan (shfl) + fp64 variance argmax.
// val_sum[t] == t * cnt[t] exactly, so only the count histogram is needed.
// ---------------------------------------------------------------------------
__global__ __launch_bounds__(1024) void otsu_thresh_k(const unsigned* __restrict__ partials,
                                                      int B,
                                                      int* __restrict__ d_out,
                                                      int* __restrict__ thresh_ws) {
    __shared__ unsigned red[4][NBINS];
    __shared__ unsigned cnt[NBINS];

    const int bin = threadIdx.x & 255;
    const int q = threadIdx.x >> 8;
    const int BQ = (B + 3) / 4;
    int r = q * BQ;
    const int e = min((q + 1) * BQ, B);
    unsigned s = 0;
    for (; r + 16 <= e; r += 16) {
#pragma unroll
        for (int k = 0; k < 16; ++k) s += partials[(r + k) * NBINS + bin];
    }
    for (; r < e; ++r) s += partials[r * NBINS + bin];
    red[q][bin] = s;
    __syncthreads();

    if (threadIdx.x < NBINS)
        cnt[bin] = red[0][bin] + red[1][bin] + red[2][bin] + red[3][bin];
    __syncthreads();

    if (threadIdx.x >= 64) return;
    const int lane = threadIdx.x;

    uint4 c4 = ((const uint4*)cnt)[lane];
    unsigned cs[4] = {c4.x, c4.y, c4.z, c4.w};

    unsigned long long lc[4], lv[4];
    unsigned long long ccum = 0ull, vcum = 0ull;
#pragma unroll
    for (int k = 0; k < 4; ++k) {
        ccum += cs[k];
        vcum += (unsigned long long)cs[k] * (unsigned)(4 * lane + k);
        lc[k] = ccum;
        lv[k] = vcum;
    }
    unsigned long long cscan = ccum, vscan = vcum;
    for (int d = 1; d < 64; d <<= 1) {
        unsigned long long cu = __shfl_up(cscan, d);
        unsigned long long vu = __shfl_up(vscan, d);
        if (lane >= d) { cscan += cu; vscan += vu; }
    }
    const unsigned long long cbase = cscan - ccum;
    const unsigned long long vbase = vscan - vcum;
    const unsigned long long vtotal = __shfl(vscan, 63);

    double best = -1.0;
    int bestt = 255;
    const double hw = (double)HW_TOTAL;
    const double vtot_d = (double)vtotal;
#pragma unroll
    for (int k = 0; k < 4; ++k) {
        int tt = 4 * lane + k;
        if (tt > 254) continue;
        double nb = (double)(cbase + lc[k]);
        double sb = (double)(vbase + lv[k]);
        double nw = hw - nb;
        double sw = vtot_d - sb;
        double dm = sb / nb - sw / nw;
        double var = nb * nw * dm * dm;
        if (var > best || (var == best && tt < bestt)) { best = var; bestt = tt; }
    }
    for (int d = 32; d >= 1; d >>= 1) {
        double ov = __shfl_xor(best, d);
        int ot = __shfl_xor(bestt, d);
        if (ov > best || (ov == best && ot < bestt)) { best = ov; bestt = ot; }
    }
    if (lane == 0) {
        d_out[0] = bestt;
        *thresh_ws = bestt;
    }
}

// ---------------------------------------------------------------------------
// Kernel 3: binarize. Output image lives at out[1..HW]; aligned out-chunk
// out[4c..4c+3] needs pixels [4c-1..4c+2], loaded directly as a dword-aligned
// (align-4) dwordx4 at img+4c-1 — no shuffles, no divergence. Reads are
// L3-hits (img staged by hist); stores stay 16 B-aligned.
// ---------------------------------------------------------------------------
__global__ __launch_bounds__(BLK, 8) void otsu_bin_k(const int* __restrict__ img,
                                                     int* __restrict__ out,
                                                     const int* __restrict__ thresh_ws) {
    const int thresh = *thresh_ws;     // uniform -> s_load
    const int t = threadIdx.x;
    const int wave = t >> 6, lane = t & 63;
    const int i0 = blockIdx.x * (BLK * BATCH) + wave * (64 * BATCH) + lane;

#pragma unroll
    for (int k = 0; k < BATCH; ++k) {
        const int c = i0 + k * 64;
        const int4a* vp = (const int4a*)(img + (c ? 4 * c - 1 : 0));
        int4a v = *vp;                 // pixels 4c-1 .. 4c+2 (c>0)
        int4n o;
        o.x = (v.x <= thresh) ? 0 : 256;
        o.y = (v.y <= thresh) ? 0 : 256;
        o.z = (v.z <= thresh) ? 0 : 256;
        o.w = (v.w <= thresh) ? 0 : 256;
        if (c == 0) {                  // single thread: v = pixels 0..3
            o.w = o.z; o.z = o.y; o.y = o.x; o.x = thresh;
        }
        *((int4n*)out + c) = o;        // aligned 16 B store
    }
    if (i0 == 0)
        out[HW_TOTAL] = (img[HW_TOTAL - 1] <= thresh) ? 0 : 256;
}

extern "C" void kernel_launch(void* const* d_in, const int* in_sizes, int n_in,
                              void* d_out, int out_size, void* d_ws, size_t ws_size,
                              hipStream_t stream) {
    const int* img = (const int*)d_in[0];
    int* out = (int*)d_out;
    int* thresh_ws = (int*)d_ws;
    unsigned* hist_buf = (unsigned*)((char*)d_ws + 256);

    if (ws_size >= (size_t)WS_NEED) {
        // partial-histogram scheme: no global atomics, no memset
        otsu_hist_k<0><<<HIST_B, BLK, 0, stream>>>((const int4*)img, hist_buf);
        otsu_thresh_k<<<1, 1024, 0, stream>>>(hist_buf, HIST_B, out, thresh_ws);
    } else {
        // fallback: atomic flush into a single 256-bin histogram
        (void)hipMemsetAsync(hist_buf, 0, NBINS * sizeof(unsigned), stream);
        otsu_hist_k<1><<<HIST_B, BLK, 0, stream>>>((const int4*)img, hist_buf);
        otsu_thresh_k<<<1, 1024, 0, stream>>>(hist_buf, 1, out, thresh_ws);
    }
    otsu_bin_k<<<HIST_B, BLK, 0, stream>>>(img, out, thresh_ws);
}